// Round 3
// baseline (93.277 us; speedup 1.0000x reference)
//
#include <hip/hip_runtime.h>

typedef __attribute__((ext_vector_type(8))) _Float16 half8;
typedef __attribute__((ext_vector_type(4))) _Float16 half4;
typedef __attribute__((ext_vector_type(4))) float f32x4;
#if __has_builtin(__builtin_amdgcn_cvt_pkrtz)
typedef __attribute__((ext_vector_type(2))) __fp16 fp16x2;
#endif

#define ALPHA 0.2f
#define LOG2E 1.44269504f

__device__ __forceinline__ void gload_lds16(const void* g, void* l) {
  __builtin_amdgcn_global_load_lds((const __attribute__((address_space(1))) unsigned int*)g,
                                   (__attribute__((address_space(3))) unsigned int*)l, 16, 0, 0);
}

__device__ __forceinline__ float fexp2(float x) {
#if __has_builtin(__builtin_amdgcn_exp2f)
  return __builtin_amdgcn_exp2f(x);
#else
  return __expf(x * 0.69314718f);
#endif
}

// ---------------- K0a: W fp32 -> fp16 (plain layout) ----------------
__global__ __launch_bounds__(256) void k_convW(const float* __restrict__ W,
                                               _Float16* __restrict__ W16) {
  int i = (blockIdx.x * 256 + threadIdx.x) * 4;
  float4 v = *reinterpret_cast<const float4*>(W + i);
  half4 hv = {(_Float16)v.x, (_Float16)v.y, (_Float16)v.z, (_Float16)v.w};
  *reinterpret_cast<half4*>(W16 + i) = hv;
}

// ---------------- K0b: u = W^T a  (one block per k) ----------------
__global__ __launch_bounds__(256) void k_uvec(const float* __restrict__ W,
                                              const float* __restrict__ a1,
                                              const float* __restrict__ a2,
                                              float* __restrict__ u1,
                                              float* __restrict__ u2) {
  __shared__ float r1[4], r2[4];
  int k = blockIdx.x, t = threadIdx.x;
  float wv = W[t * 512 + k];
  float x1 = wv * a1[t];
  float x2 = wv * a2[t];
#pragma unroll
  for (int off = 32; off >= 1; off >>= 1) {
    x1 += __shfl_xor(x1, off);
    x2 += __shfl_xor(x2, off);
  }
  if ((t & 63) == 0) { r1[t >> 6] = x1; r2[t >> 6] = x2; }
  __syncthreads();
  if (t == 0) {
    u1[k] = r1[0] + r1[1] + r1[2] + r1[3];
    u2[k] = r2[0] + r2[1] + r2[2] + r2[3];
  }
}

// ---------------- K1b: per-batch max of s2, plus s2L = log2e * s2 ----------------
__global__ __launch_bounds__(256) void k_smax(const float* __restrict__ s2,
                                              float* __restrict__ smax,
                                              float* __restrict__ s2L) {
  __shared__ float red[4];
  int b = blockIdx.x, t = threadIdx.x;
  float m = -1e30f;
  for (int j = t; j < 2048; j += 256) {
    float v = s2[b * 2048 + j];
    s2L[b * 2048 + j] = LOG2E * v;
    m = fmaxf(m, v);
  }
#pragma unroll
  for (int off = 32; off >= 1; off >>= 1) m = fmaxf(m, __shfl_xor(m, off));
  if ((t & 63) == 0) red[t >> 6] = m;
  __syncthreads();
  if (t == 0) smax[b] = fmaxf(fmaxf(red[0], red[1]), fmaxf(red[2], red[3]));
}

// ---------------- K2: Wh GEMM + fused s1/s2, writes SWIZZLED WhT[b][c][n] ----------------
// 1024 blocks x 256 thr; block = 16 rows x 256 cols; wave = 16 rows x 64 cols (ni=4).
// A staged in LDS dbuf (4 KB); B (W16, 256 KB) read directly from global (L2-resident).
__global__ __launch_bounds__(256) void k_gemm_wh(const float* __restrict__ h,
                                                 const _Float16* __restrict__ W16,
                                                 const float* __restrict__ u1,
                                                 const float* __restrict__ u2,
                                                 float* __restrict__ s1o,
                                                 float* __restrict__ s2o,
                                                 _Float16* __restrict__ WhT) {
  __shared__ _Float16 As[2][16 * 64];  // 2 KB each, XOR-swizzled
  const int t = threadIdx.x, lane = t & 63, w = t >> 6;
  const int i0 = blockIdx.x * 16;  // global row 0..16383
  const int b = i0 >> 11;
  const int arow = lane & 15;
  const int srow = t >> 4;          // staging row 0..15
  const int sch = (t & 15) * 4;     // staging k-chunk (floats)
  const float* hrow = h + (size_t)(i0 + srow) * 512 + sch;

  f32x4 acc[4];
#pragma unroll
  for (int ni = 0; ni < 4; ++ni) acc[ni] = (f32x4){0.f, 0.f, 0.f, 0.f};
  float x1 = 0.f, x2 = 0.f;

  // prologue: stage A(0) + fused s1/s2 partial
  {
    float4 aR = *reinterpret_cast<const float4*>(hrow);
    float4 ua = *reinterpret_cast<const float4*>(u1 + sch);
    float4 ub = *reinterpret_cast<const float4*>(u2 + sch);
    x1 += aR.x * ua.x + aR.y * ua.y + aR.z * ua.z + aR.w * ua.w;
    x2 += aR.x * ub.x + aR.y * ub.y + aR.z * ub.z + aR.w * ub.w;
    half4 hv = {(_Float16)aR.x, (_Float16)aR.y, (_Float16)aR.z, (_Float16)aR.w};
    *reinterpret_cast<half4*>((char*)&As[0][0] + srow * 128 + ((sch * 2) ^ ((srow & 7) << 4))) = hv;
  }
  for (int kt = 0; kt < 8; ++kt) {
    __syncthreads();  // publishes A(kt)
    if (kt < 7) {
      const int k0 = (kt + 1) * 64;
      float4 aR = *reinterpret_cast<const float4*>(hrow + k0);
      float4 ua = *reinterpret_cast<const float4*>(u1 + k0 + sch);
      float4 ub = *reinterpret_cast<const float4*>(u2 + k0 + sch);
      x1 += aR.x * ua.x + aR.y * ua.y + aR.z * ua.z + aR.w * ua.w;
      x2 += aR.x * ub.x + aR.y * ub.y + aR.z * ub.z + aR.w * ub.w;
      half4 hv = {(_Float16)aR.x, (_Float16)aR.y, (_Float16)aR.z, (_Float16)aR.w};
      *reinterpret_cast<half4*>((char*)&As[(kt + 1) & 1][0] + srow * 128 + ((sch * 2) ^ ((srow & 7) << 4))) = hv;
    }
    const char* Ac = (const char*)&As[kt & 1][0];
#pragma unroll
    for (int kk = 0; kk < 2; ++kk) {
      const int koff = (lane >> 4) * 16 + kk * 64;
      half8 afr = *reinterpret_cast<const half8*>(Ac + arow * 128 + (koff ^ ((arow & 7) << 4)));
      const int kg = kt * 64 + kk * 32 + (lane >> 4) * 8;
#pragma unroll
      for (int ni = 0; ni < 4; ++ni) {
        int n = 64 * w + 16 * ni + arow;
        half8 bfr = *reinterpret_cast<const half8*>(W16 + n * 512 + kg);
        acc[ni] = __builtin_amdgcn_mfma_f32_16x16x32_f16(afr, bfr, acc[ni], 0, 0, 0);
      }
    }
  }
  // s1/s2: reduce over 16 lanes sharing a row
  x1 += __shfl_xor(x1, 1); x1 += __shfl_xor(x1, 2); x1 += __shfl_xor(x1, 4); x1 += __shfl_xor(x1, 8);
  x2 += __shfl_xor(x2, 1); x2 += __shfl_xor(x2, 2); x2 += __shfl_xor(x2, 4); x2 += __shfl_xor(x2, 8);
  if ((t & 15) == 0) { s1o[i0 + srow] = x1; s2o[i0 + srow] = x2; }
  // epilogue: pre-swizzled WhT store (unit8 XOR (c&7), within 64-n blocks)
  _Float16* whtb = WhT + (size_t)b * 256 * 2048;
  const int nb = (i0 & 2047) + (lane >> 4) * 4;
#pragma unroll
  for (int ni = 0; ni < 4; ++ni) {
    int c = 64 * w + 16 * ni + arow;
    int np = nb ^ ((c & 7) << 3);
    f32x4 a = acc[ni];
    half4 hv = {(_Float16)a[0], (_Float16)a[1], (_Float16)a[2], (_Float16)a[3]};
    *reinterpret_cast<half4*>(whtb + (size_t)c * 2048 + np) = hv;
  }
}

// ---------------- K3: fused softmax(P) @ Wh + ELU ----------------
// 1024 blocks: bid&7 = batch (XCD affinity), 32 row-blocks x 4 col-groups.
// wave = 16 rows x 64 cols (ni=4); denominator via ones-column MFMA.
__global__ __launch_bounds__(256) void k_attn(const _Float16* __restrict__ WhT,
                                              const float* __restrict__ s1,
                                              const float* __restrict__ s2L,
                                              const float* __restrict__ smax,
                                              float* __restrict__ out) {
  __shared__ _Float16 Bb[2][64 * 64];  // 8 KB each
  const int t = threadIdx.x, lane = t & 63, w = t >> 6;
  const int bid = blockIdx.x;
  const int b = bid & 7;
  const int ib = (bid >> 3) & 31;
  const int cg = bid >> 8;
  const int i0 = ib * 64, c0 = cg * 64;
  const _Float16* whtb = WhT + ((size_t)b * 256 + c0) * 2048;
  const float* s2Lb = s2L + b * 2048;
  const int arow = lane & 15;
  const int grow = i0 + w * 16 + arow;
  const float s1v = s1[b * 2048 + grow];
  const float sm = smax[b];
  const float e0 = s1v + sm;
  const float mrow = fmaxf(e0, ALPHA * e0);  // closed-form row max (LeakyReLU monotonic)
  const float C1 = LOG2E * (s1v - mrow);
  const float C2 = fmaf(ALPHA * LOG2E, s1v, -LOG2E * mrow);
  half8 onesb;
  {
    _Float16 ov = (arow == 0) ? (_Float16)1.0f : (_Float16)0.0f;
#pragma unroll
    for (int x = 0; x < 8; ++x) onesb[x] = ov;
  }
  f32x4 acc[4];
#pragma unroll
  for (int ni = 0; ni < 4; ++ni) acc[ni] = (f32x4){0.f, 0.f, 0.f, 0.f};
  f32x4 accd = (f32x4){0.f, 0.f, 0.f, 0.f};

  // prologue: stage tile 0
#pragma unroll
  for (int q = 0; q < 2; ++q) {
    int idx = q * 256 + t;
    int cl = idx >> 3, uu = idx & 7;
    gload_lds16(whtb + (size_t)cl * 2048 + uu * 8, (char*)&Bb[0][0] + idx * 16);
  }

  for (int jt = 0; jt < 32; ++jt) {
    const int cur = jt & 1;
    __syncthreads();  // drains B(jt) loads; orders buffer reuse
    if (jt < 31) {
      const int j0n = (jt + 1) * 64;
#pragma unroll
      for (int q = 0; q < 2; ++q) {
        int idx = q * 256 + t;
        int cl = idx >> 3, uu = idx & 7;
        gload_lds16(whtb + (size_t)cl * 2048 + j0n + uu * 8, (char*)&Bb[cur ^ 1][0] + idx * 16);
      }
    }
    const int j0 = jt * 64;
    const char* Bc = (const char*)&Bb[cur][0];
#pragma unroll
    for (int kk = 0; kk < 2; ++kk) {
      const int jl = (lane >> 4) * 8 + kk * 32;
      float4 sA = *reinterpret_cast<const float4*>(s2Lb + j0 + jl);
      float4 sB = *reinterpret_cast<const float4*>(s2Lb + j0 + jl + 4);
      float p0 = fexp2(fmaxf(C1 + sA.x, fmaf(ALPHA, sA.x, C2)));
      float p1 = fexp2(fmaxf(C1 + sA.y, fmaf(ALPHA, sA.y, C2)));
      float p2 = fexp2(fmaxf(C1 + sA.z, fmaf(ALPHA, sA.z, C2)));
      float p3 = fexp2(fmaxf(C1 + sA.w, fmaf(ALPHA, sA.w, C2)));
      float p4 = fexp2(fmaxf(C1 + sB.x, fmaf(ALPHA, sB.x, C2)));
      float p5 = fexp2(fmaxf(C1 + sB.y, fmaf(ALPHA, sB.y, C2)));
      float p6 = fexp2(fmaxf(C1 + sB.z, fmaf(ALPHA, sB.z, C2)));
      float p7 = fexp2(fmaxf(C1 + sB.w, fmaf(ALPHA, sB.w, C2)));
      half8 afr;
#if __has_builtin(__builtin_amdgcn_cvt_pkrtz)
      {
        fp16x2 q0 = __builtin_amdgcn_cvt_pkrtz(p0, p1);
        fp16x2 q1 = __builtin_amdgcn_cvt_pkrtz(p2, p3);
        fp16x2 q2 = __builtin_amdgcn_cvt_pkrtz(p4, p5);
        fp16x2 q3 = __builtin_amdgcn_cvt_pkrtz(p6, p7);
        afr[0] = (_Float16)q0[0]; afr[1] = (_Float16)q0[1];
        afr[2] = (_Float16)q1[0]; afr[3] = (_Float16)q1[1];
        afr[4] = (_Float16)q2[0]; afr[5] = (_Float16)q2[1];
        afr[6] = (_Float16)q3[0]; afr[7] = (_Float16)q3[1];
      }
#else
      afr[0] = (_Float16)p0; afr[1] = (_Float16)p1; afr[2] = (_Float16)p2; afr[3] = (_Float16)p3;
      afr[4] = (_Float16)p4; afr[5] = (_Float16)p5; afr[6] = (_Float16)p6; afr[7] = (_Float16)p7;
#endif
      // denominator: ones-column MFMA accumulates row-sums of fp16 P (consistent rounding)
      accd = __builtin_amdgcn_mfma_f32_16x16x32_f16(afr, onesb, accd, 0, 0, 0);
      const int jb = jl * 2;
#pragma unroll
      for (int ni = 0; ni < 4; ++ni) {
        int cl = 16 * ni + arow;
        half8 bfr = *reinterpret_cast<const half8*>(Bc + cl * 128 + (jb ^ ((cl & 7) << 4)));
        acc[ni] = __builtin_amdgcn_mfma_f32_16x16x32_f16(afr, bfr, acc[ni], 0, 0, 0);
      }
    }
  }
  // epilogue: fetch row-sum from col-0 lane, divide, ELU, store fp32
  const size_t ob = ((size_t)b * 2048 + i0 + w * 16) * 256 + c0;
#pragma unroll
  for (int reg = 0; reg < 4; ++reg) {
    float dv = __shfl(accd[reg], lane & 48);
    float inv = 1.0f / dv;
    int rr = (lane >> 4) * 4 + reg;
#pragma unroll
    for (int ni = 0; ni < 4; ++ni) {
      int c = 16 * ni + arow;
      float v = acc[ni][reg] * inv;
      v = v > 0.f ? v : (__expf(v) - 1.f);
      out[ob + (size_t)rr * 256 + c] = v;
    }
  }
}

extern "C" void kernel_launch(void* const* d_in, const int* in_sizes, int n_in,
                              void* d_out, int out_size, void* d_ws, size_t ws_size,
                              hipStream_t stream) {
  (void)in_sizes; (void)n_in; (void)out_size; (void)ws_size;
  const float* h = (const float*)d_in[0];
  const float* W = (const float*)d_in[1];
  const float* a1 = (const float*)d_in[2];
  const float* a2 = (const float*)d_in[3];
  float* out = (float*)d_out;
  char* ws = (char*)d_ws;
  _Float16* WhT = (_Float16*)(ws);             // 8*256*2048*2 = 8388608 B (pre-swizzled)
  _Float16* W16 = (_Float16*)(ws + 8388608);   // 262144 B (plain)
  float* u1 = (float*)(ws + 8650752);          // 2048 B
  float* u2 = (float*)(ws + 8652800);          // 2048 B
  float* s1 = (float*)(ws + 8654848);          // 65536 B
  float* s2 = (float*)(ws + 8720384);          // 65536 B
  float* smax = (float*)(ws + 8785920);        // 32 B
  float* s2L = (float*)(ws + 8785952);         // 65536 B

  hipLaunchKernelGGL(k_convW, dim3(128), dim3(256), 0, stream, W, W16);
  hipLaunchKernelGGL(k_uvec, dim3(512), dim3(256), 0, stream, W, a1, a2, u1, u2);
  hipLaunchKernelGGL(k_gemm_wh, dim3(1024), dim3(256), 0, stream, h, W16, u1, u2, s1, s2, WhT);
  hipLaunchKernelGGL(k_smax, dim3(8), dim3(256), 0, stream, s2, smax, s2L);
  hipLaunchKernelGGL(k_attn, dim3(1024), dim3(256), 0, stream, WhT, s1, s2L, smax, out);
}

// Round 4
// 70.869 us; speedup vs baseline: 1.3162x; 1.3162x over previous
//
#include <hip/hip_runtime.h>

typedef __attribute__((ext_vector_type(8))) _Float16 half8;
typedef __attribute__((ext_vector_type(4))) _Float16 half4;
typedef __attribute__((ext_vector_type(4))) float f32x4;
#if __has_builtin(__builtin_amdgcn_cvt_pkrtz)
typedef __attribute__((ext_vector_type(2))) __fp16 fp16x2;
#endif

#define ALPHA 0.2f
#define LOG2E 1.44269504f

__device__ __forceinline__ void gload_lds16(const void* g, void* l) {
  __builtin_amdgcn_global_load_lds((const __attribute__((address_space(1))) unsigned int*)g,
                                   (__attribute__((address_space(3))) unsigned int*)l, 16, 0, 0);
}

__device__ __forceinline__ float fexp2(float x) {
#if __has_builtin(__builtin_amdgcn_exp2f)
  return __builtin_amdgcn_exp2f(x);
#else
  return __expf(x * 0.69314718f);
#endif
}

// ---------------- K0a: W fp32 -> fp16, PRE-SWIZZLED (unit8 XOR (n&7)) ----------------
__global__ __launch_bounds__(256) void k_convW(const float* __restrict__ W,
                                               _Float16* __restrict__ W16) {
  int idx4 = blockIdx.x * 256 + threadIdx.x;  // half4 unit
  int n = idx4 >> 7;                          // row 0..255
  int q = idx4 & 127;                         // half4 within row
  float4 v = *reinterpret_cast<const float4*>(W + n * 512 + q * 4);
  half4 hv = {(_Float16)v.x, (_Float16)v.y, (_Float16)v.z, (_Float16)v.w};
  int kp = (q * 4) ^ ((n & 7) << 3);          // swizzle within 64-elem blocks
  *reinterpret_cast<half4*>(W16 + n * 512 + kp) = hv;
}

// ---------------- K0b: u = W^T a  (one block per k) ----------------
__global__ __launch_bounds__(256) void k_uvec(const float* __restrict__ W,
                                              const float* __restrict__ a1,
                                              const float* __restrict__ a2,
                                              float* __restrict__ u1,
                                              float* __restrict__ u2) {
  __shared__ float r1[4], r2[4];
  int k = blockIdx.x, t = threadIdx.x;
  float wv = W[t * 512 + k];
  float x1 = wv * a1[t];
  float x2 = wv * a2[t];
#pragma unroll
  for (int off = 32; off >= 1; off >>= 1) {
    x1 += __shfl_xor(x1, off);
    x2 += __shfl_xor(x2, off);
  }
  if ((t & 63) == 0) { r1[t >> 6] = x1; r2[t >> 6] = x2; }
  __syncthreads();
  if (t == 0) {
    u1[k] = r1[0] + r1[1] + r1[2] + r1[3];
    u2[k] = r2[0] + r2[1] + r2[2] + r2[3];
  }
}

// ---------------- K1b: per-batch max of s2, plus s2L = log2e * s2 ----------------
__global__ __launch_bounds__(256) void k_smax(const float* __restrict__ s2,
                                              float* __restrict__ smax,
                                              float* __restrict__ s2L) {
  __shared__ float red[4];
  int b = blockIdx.x, t = threadIdx.x;
  float m = -1e30f;
  for (int j = t; j < 2048; j += 256) {
    float v = s2[b * 2048 + j];
    s2L[b * 2048 + j] = LOG2E * v;
    m = fmaxf(m, v);
  }
#pragma unroll
  for (int off = 32; off >= 1; off >>= 1) m = fmaxf(m, __shfl_xor(m, off));
  if ((t & 63) == 0) red[t >> 6] = m;
  __syncthreads();
  if (t == 0) smax[b] = fmaxf(fmaxf(red[0], red[1]), fmaxf(red[2], red[3]));
}

// ---------------- K2: Wh GEMM + fused s1/s2 (R2-proven structure) ----------------
// block: 32 rows x 256 cols, 4 waves (each 32x64), 512 blocks (2/CU)
__global__ __launch_bounds__(256) void k_gemm_wh(const float* __restrict__ h,
                                                 const _Float16* __restrict__ W16,
                                                 const float* __restrict__ u1,
                                                 const float* __restrict__ u2,
                                                 float* __restrict__ s1o,
                                                 float* __restrict__ s2o,
                                                 _Float16* __restrict__ WhT) {
  __shared__ _Float16 Ab[2][32 * 64];    // 4 KB each, swizzled (reg-staged)
  __shared__ _Float16 Bb[2][256 * 64];   // 32 KB each, linear copy of pre-swizzled W16
  const int t = threadIdx.x, lane = t & 63, w = t >> 6;
  const int i0 = blockIdx.x * 32;        // global row 0..16383
  const int b = i0 >> 11, n0 = i0 & 2047;
  const int ar = t >> 3, au = t & 7;     // A-stage: row 0..31, 8-float chunk 0..7
  const float* hrow = h + (size_t)(i0 + ar) * 512 + au * 8;

  f32x4 acc[2][4];
#pragma unroll
  for (int mi = 0; mi < 2; ++mi)
#pragma unroll
    for (int ni = 0; ni < 4; ++ni) acc[mi][ni] = (f32x4){0.f, 0.f, 0.f, 0.f};

  // prologue: load A(0) regs, stage B(0) via global_load_lds
  float4 aR0 = *reinterpret_cast<const float4*>(hrow);
  float4 aR1 = *reinterpret_cast<const float4*>(hrow + 4);
#pragma unroll
  for (int q = 0; q < 8; ++q) {
    int idx = (q * 4 + w) * 64 + lane;
    int nn = idx >> 3, uu = idx & 7;
    gload_lds16(W16 + nn * 512 + uu * 8, (char*)&Bb[0][0] + idx * 16);
  }
  float x1 = 0.f, x2 = 0.f;

  for (int kt = 0; kt < 8; ++kt) {
    const int cur = kt & 1;
    // ds_write A(kt) (+ fused s1/s2 partials on the same registers)
    {
      half8 av;
      av[0] = (_Float16)aR0.x; av[1] = (_Float16)aR0.y;
      av[2] = (_Float16)aR0.z; av[3] = (_Float16)aR0.w;
      av[4] = (_Float16)aR1.x; av[5] = (_Float16)aR1.y;
      av[6] = (_Float16)aR1.z; av[7] = (_Float16)aR1.w;
      *reinterpret_cast<half8*>((char*)&Ab[cur][0] + ar * 128 + ((au * 16) ^ ((ar & 7) << 4))) = av;
      const float* up1 = u1 + kt * 64 + au * 8;
      const float* up2 = u2 + kt * 64 + au * 8;
      float4 u1a = *reinterpret_cast<const float4*>(up1);
      float4 u1b = *reinterpret_cast<const float4*>(up1 + 4);
      float4 u2a = *reinterpret_cast<const float4*>(up2);
      float4 u2b = *reinterpret_cast<const float4*>(up2 + 4);
      x1 += aR0.x * u1a.x + aR0.y * u1a.y + aR0.z * u1a.z + aR0.w * u1a.w
          + aR1.x * u1b.x + aR1.y * u1b.y + aR1.z * u1b.z + aR1.w * u1b.w;
      x2 += aR0.x * u2a.x + aR0.y * u2a.y + aR0.z * u2a.z + aR0.w * u2a.w
          + aR1.x * u2b.x + aR1.y * u2b.y + aR1.z * u2b.z + aR1.w * u2b.w;
    }
    __syncthreads();  // A(kt) visible; B(kt) loads drained
    if (kt < 7) {     // prefetch tile kt+1 (lands during compute below)
      const int k0 = (kt + 1) * 64;
      aR0 = *reinterpret_cast<const float4*>(hrow + k0);
      aR1 = *reinterpret_cast<const float4*>(hrow + k0 + 4);
#pragma unroll
      for (int q = 0; q < 8; ++q) {
        int idx = (q * 4 + w) * 64 + lane;
        int nn = idx >> 3, uu = idx & 7;
        gload_lds16(W16 + nn * 512 + k0 + uu * 8, (char*)&Bb[cur ^ 1][0] + idx * 16);
      }
    }
    // compute tile kt
    const char* Ac = (const char*)&Ab[cur][0];
    const char* Bc = (const char*)&Bb[cur][0];
#pragma unroll
    for (int kk = 0; kk < 2; ++kk) {
      const int jb = (lane >> 4) * 16 + kk * 64;
      half8 afr[2];
#pragma unroll
      for (int mi = 0; mi < 2; ++mi) {
        int rr = (lane & 15) + 16 * mi;
        afr[mi] = *reinterpret_cast<const half8*>(Ac + rr * 128 + (jb ^ ((rr & 7) << 4)));
      }
#pragma unroll
      for (int ni = 0; ni < 4; ++ni) {
        int nn = 64 * w + 16 * ni + (lane & 15);
        half8 bfr = *reinterpret_cast<const half8*>(Bc + nn * 128 + (jb ^ ((nn & 7) << 4)));
#pragma unroll
        for (int mi = 0; mi < 2; ++mi)
          acc[mi][ni] = __builtin_amdgcn_mfma_f32_16x16x32_f16(afr[mi], bfr, acc[mi][ni], 0, 0, 0);
      }
    }
  }
  // s1/s2: reduce over the 8 threads sharing a row (contiguous lanes)
  x1 += __shfl_xor(x1, 1); x1 += __shfl_xor(x1, 2); x1 += __shfl_xor(x1, 4);
  x2 += __shfl_xor(x2, 1); x2 += __shfl_xor(x2, 2); x2 += __shfl_xor(x2, 4);
  if (au == 0) { s1o[i0 + ar] = x1; s2o[i0 + ar] = x2; }
  // epilogue: pre-swizzled WhT store (unit8 XOR (c&7), within 64-n blocks)
  _Float16* whtb = WhT + (size_t)b * 256 * 2048;
#pragma unroll
  for (int mi = 0; mi < 2; ++mi)
#pragma unroll
    for (int ni = 0; ni < 4; ++ni) {
      int c = 64 * w + 16 * ni + (lane & 15);
      int nb = n0 + 16 * mi + (lane >> 4) * 4;
      int np = nb ^ ((c & 7) << 3);
      f32x4 a = acc[mi][ni];
      half4 hv = {(_Float16)a[0], (_Float16)a[1], (_Float16)a[2], (_Float16)a[3]};
      *reinterpret_cast<half4*>(whtb + (size_t)c * 2048 + np) = hv;
    }
}

// ---------------- K3: fused softmax(P) @ Wh + ELU, shared-P (dup=1) ----------------
// 512 blocks x 512 thr: bid&7 = batch (XCD affinity), bid>>3 = 32-row block.
// 8 waves = 2 row-groups x 4 col-groups; P tile (32x64) built ONCE per j-step in LDS.
__global__ __launch_bounds__(512) void k_attn(const _Float16* __restrict__ WhT,
                                              const float* __restrict__ s1,
                                              const float* __restrict__ s2L,
                                              const float* __restrict__ smax,
                                              float* __restrict__ out) {
  __shared__ _Float16 Bb[2][256 * 64];  // 32 KB each
  __shared__ _Float16 Pb[2][32 * 64];   // 4 KB each
  __shared__ float d_lds[32];
  const int t = threadIdx.x, lane = t & 63, w = t >> 6;
  const int rg = w >> 2, cg = w & 3;
  const int bid = blockIdx.x;
  const int b = bid & 7;
  const int i0 = (bid >> 3) * 32;
  const _Float16* whtb = WhT + (size_t)b * 256 * 2048;
  const float* s2Lb = s2L + b * 2048;
  const int arow = lane & 15;
  const float sm = smax[b];
  // P-build role: thread t computes row pr, 4 j's starting at pj*4
  const int pr = t >> 4, pj = t & 15;
  const float s1p = s1[b * 2048 + i0 + pr];
  const float e0p = s1p + sm;
  const float mrowp = fmaxf(e0p, ALPHA * e0p);  // closed-form row max (LR monotonic)
  const float C1 = LOG2E * (s1p - mrowp);
  const float C2 = fmaf(ALPHA * LOG2E, s1p, -LOG2E * mrowp);
  const int pwoff = pr * 128 + ((pj * 8) ^ ((pr & 7) << 4));  // swizzled 8B slot
  half8 onesb;
  {
    _Float16 ov = (arow == 0) ? (_Float16)1.0f : (_Float16)0.0f;
#pragma unroll
    for (int x = 0; x < 8; ++x) onesb[x] = ov;
  }
  f32x4 acc[4];
#pragma unroll
  for (int ni = 0; ni < 4; ++ni) acc[ni] = (f32x4){0.f, 0.f, 0.f, 0.f};
  f32x4 accd = (f32x4){0.f, 0.f, 0.f, 0.f};

  // prologue: stage B(0), build P(0)
#pragma unroll
  for (int q = 0; q < 4; ++q) {
    int idx = q * 512 + t;
    int cl = idx >> 3, uu = idx & 7;
    gload_lds16(whtb + (size_t)cl * 2048 + uu * 8, (char*)&Bb[0][0] + idx * 16);
  }
  {
    float4 sv = *reinterpret_cast<const float4*>(s2Lb + pj * 4);
    float p0 = fexp2(fmaxf(C1 + sv.x, fmaf(ALPHA, sv.x, C2)));
    float p1 = fexp2(fmaxf(C1 + sv.y, fmaf(ALPHA, sv.y, C2)));
    float p2 = fexp2(fmaxf(C1 + sv.z, fmaf(ALPHA, sv.z, C2)));
    float p3 = fexp2(fmaxf(C1 + sv.w, fmaf(ALPHA, sv.w, C2)));
    half4 hv;
#if __has_builtin(__builtin_amdgcn_cvt_pkrtz)
    fp16x2 q0 = __builtin_amdgcn_cvt_pkrtz(p0, p1);
    fp16x2 q1 = __builtin_amdgcn_cvt_pkrtz(p2, p3);
    hv[0] = (_Float16)q0[0]; hv[1] = (_Float16)q0[1];
    hv[2] = (_Float16)q1[0]; hv[3] = (_Float16)q1[1];
#else
    hv[0] = (_Float16)p0; hv[1] = (_Float16)p1; hv[2] = (_Float16)p2; hv[3] = (_Float16)p3;
#endif
    *reinterpret_cast<half4*>((char*)&Pb[0][0] + pwoff) = hv;
  }

  for (int jt = 0; jt < 32; ++jt) {
    const int cur = jt & 1;
    __syncthreads();  // B(jt)/P(jt) ready; prior reads of [cur^1] done
    if (jt < 31) {
      const int j0n = (jt + 1) * 64;
#pragma unroll
      for (int q = 0; q < 4; ++q) {
        int idx = q * 512 + t;
        int cl = idx >> 3, uu = idx & 7;
        gload_lds16(whtb + (size_t)cl * 2048 + j0n + uu * 8, (char*)&Bb[cur ^ 1][0] + idx * 16);
      }
      float4 sv = *reinterpret_cast<const float4*>(s2Lb + j0n + pj * 4);
      float p0 = fexp2(fmaxf(C1 + sv.x, fmaf(ALPHA, sv.x, C2)));
      float p1 = fexp2(fmaxf(C1 + sv.y, fmaf(ALPHA, sv.y, C2)));
      float p2 = fexp2(fmaxf(C1 + sv.z, fmaf(ALPHA, sv.z, C2)));
      float p3 = fexp2(fmaxf(C1 + sv.w, fmaf(ALPHA, sv.w, C2)));
      half4 hv;
#if __has_builtin(__builtin_amdgcn_cvt_pkrtz)
      fp16x2 q0 = __builtin_amdgcn_cvt_pkrtz(p0, p1);
      fp16x2 q1 = __builtin_amdgcn_cvt_pkrtz(p2, p3);
      hv[0] = (_Float16)q0[0]; hv[1] = (_Float16)q0[1];
      hv[2] = (_Float16)q1[0]; hv[3] = (_Float16)q1[1];
#else
      hv[0] = (_Float16)p0; hv[1] = (_Float16)p1; hv[2] = (_Float16)p2; hv[3] = (_Float16)p3;
#endif
      *reinterpret_cast<half4*>((char*)&Pb[cur ^ 1][0] + pwoff) = hv;
    }
    const char* Bc = (const char*)&Bb[cur][0];
    const char* Pc = (const char*)&Pb[cur][0];
#pragma unroll
    for (int kk = 0; kk < 2; ++kk) {
      const int jb = ((lane >> 4) * 8 + kk * 32) * 2;  // byte offset of 8-j chunk
      const int ar32 = rg * 16 + arow;
      half8 afr = *reinterpret_cast<const half8*>(Pc + ar32 * 128 + (jb ^ ((ar32 & 7) << 4)));
      if (cg == 0)  // denominator: ones-column MFMA (row-sums of fp16 P)
        accd = __builtin_amdgcn_mfma_f32_16x16x32_f16(afr, onesb, accd, 0, 0, 0);
#pragma unroll
      for (int ni = 0; ni < 4; ++ni) {
        int cl = cg * 64 + 16 * ni + arow;
        half8 bfr = *reinterpret_cast<const half8*>(Bc + cl * 128 + (jb ^ ((cl & 7) << 4)));
        acc[ni] = __builtin_amdgcn_mfma_f32_16x16x32_f16(afr, bfr, acc[ni], 0, 0, 0);
      }
    }
  }
  // publish row denominators (col 0 of accd holds row-sums)
  if (cg == 0 && arow == 0) {
#pragma unroll
    for (int reg = 0; reg < 4; ++reg)
      d_lds[rg * 16 + (lane >> 4) * 4 + reg] = accd[reg];
  }
  __syncthreads();
  // epilogue: divide, ELU, store fp32
  const size_t ob = ((size_t)b * 2048 + i0 + rg * 16) * 256 + cg * 64;
#pragma unroll
  for (int reg = 0; reg < 4; ++reg) {
    int rr = (lane >> 4) * 4 + reg;
    float inv = 1.0f / d_lds[rg * 16 + rr];
#pragma unroll
    for (int ni = 0; ni < 4; ++ni) {
      int c = 16 * ni + arow;
      float v = acc[ni][reg] * inv;
      v = v > 0.f ? v : (__expf(v) - 1.f);
      out[ob + (size_t)rr * 256 + c] = v;
    }
  }
}

extern "C" void kernel_launch(void* const* d_in, const int* in_sizes, int n_in,
                              void* d_out, int out_size, void* d_ws, size_t ws_size,
                              hipStream_t stream) {
  (void)in_sizes; (void)n_in; (void)out_size; (void)ws_size;
  const float* h = (const float*)d_in[0];
  const float* W = (const float*)d_in[1];
  const float* a1 = (const float*)d_in[2];
  const float* a2 = (const float*)d_in[3];
  float* out = (float*)d_out;
  char* ws = (char*)d_ws;
  _Float16* WhT = (_Float16*)(ws);             // 8*256*2048*2 = 8388608 B (pre-swizzled)
  _Float16* W16 = (_Float16*)(ws + 8388608);   // 262144 B (pre-swizzled)
  float* u1 = (float*)(ws + 8650752);          // 2048 B
  float* u2 = (float*)(ws + 8652800);          // 2048 B
  float* s1 = (float*)(ws + 8654848);          // 65536 B
  float* s2 = (float*)(ws + 8720384);          // 65536 B
  float* smax = (float*)(ws + 8785920);        // 32 B
  float* s2L = (float*)(ws + 8785952);         // 65536 B

  hipLaunchKernelGGL(k_convW, dim3(128), dim3(256), 0, stream, W, W16);
  hipLaunchKernelGGL(k_uvec, dim3(512), dim3(256), 0, stream, W, a1, a2, u1, u2);
  hipLaunchKernelGGL(k_gemm_wh, dim3(512), dim3(256), 0, stream, h, W16, u1, u2, s1, s2, WhT);
  hipLaunchKernelGGL(k_smax, dim3(8), dim3(256), 0, stream, s2, smax, s2L);
  hipLaunchKernelGGL(k_attn, dim3(512), dim3(512), 0, stream, WhT, s1, s2L, smax, out);
}